// Round 2
// baseline (717.864 us; speedup 1.0000x reference)
//
#include <hip/hip_runtime.h>
#include <stdint.h>

#define HH 64      // hidden
#define II 32      // input features
#define TSTEPS 512
#define BATCH 1024
#define CH 64      // timesteps per LDS x-chunk
#define NCH (TSTEPS / CH)
#define WPB 4      // waves (batch elements) per block

// broadcast lane j's value to all lanes via v_readlane (VALU/SGPR path, no LDS)
__device__ __forceinline__ float bcastf(float v, int lane) {
    return __int_as_float(__builtin_amdgcn_readlane(__float_as_int(v), lane));
}

// tanh(x) = 1 - 2/(exp(2x)+1); hw exp2 + hw rcp, ~1e-7 abs err, saturates
// correctly at +/-inf (exp2->inf -> rcp->0 -> 1 ; exp2->0 -> 1-2 = -1)
__device__ __forceinline__ float fast_tanh(float x) {
    float e = __builtin_amdgcn_exp2f(x * 2.885390081777927f); // 2*log2(e)
    return 1.0f - 2.0f * __builtin_amdgcn_rcpf(e + 1.0f);
}

// stage 8KB (64 timesteps x 32 floats) global -> LDS, linear, 8x 16B/lane
__device__ __forceinline__ void stage8k(const float* g, float* l, int lane) {
#pragma unroll
    for (int k = 0; k < 8; ++k) {
        __builtin_amdgcn_global_load_lds(
            (const __attribute__((address_space(1))) void*)(g + k * 256 + lane * 4),
            (__attribute__((address_space(3))) void*)(l + k * 256),
            16, 0, 0);
    }
}

// load one timestep row (32 floats) LDS -> 8x float4 regs (uniform broadcast reads)
#define LOADX(dst, rp)                                                        \
    {                                                                         \
        _Pragma("unroll") for (int k = 0; k < 8; ++k)                         \
            dst[k] = ((const float4*)(rp))[k];                                \
    }

// one fused timestep: layer1 (ih from regs, hh pre-accumulated), layer2,
// and pre-accumulation of both next-step recurrent terms.
#define STEP(xv)                                                              \
    {                                                                         \
        float a0 = acc1p, a1 = 0.f, a2 = 0.f, a3 = 0.f;                       \
        _Pragma("unroll") for (int i = 0; i < 8; ++i) {                       \
            a0 = fmaf(xv[i].x, wih1[4 * i + 0], a0);                          \
            a1 = fmaf(xv[i].y, wih1[4 * i + 1], a1);                          \
            a2 = fmaf(xv[i].z, wih1[4 * i + 2], a2);                          \
            a3 = fmaf(xv[i].w, wih1[4 * i + 3], a3);                          \
        }                                                                     \
        float h1 = fast_tanh((a0 + a1) + (a2 + a3));                          \
        float c0 = acc2p, c1 = 0.f;  /* layer2 pre-act partials */            \
        float p0 = b1, p1 = 0.f;     /* next-step layer1 recurrent partials */\
        _Pragma("unroll") for (int j = 0; j < HH; j += 2) {                   \
            float s0 = bcastf(h1, j);                                         \
            float s1 = bcastf(h1, j + 1);                                     \
            c0 = fmaf(s0, wih2[j], c0);                                       \
            c1 = fmaf(s1, wih2[j + 1], c1);                                   \
            p0 = fmaf(s0, whh1[j], p0);                                       \
            p1 = fmaf(s1, whh1[j + 1], p1);                                   \
        }                                                                     \
        acc1p = p0 + p1;                                                      \
        h2 = fast_tanh(c0 + c1);                                              \
        float q0 = b2, q1 = 0.f;                                              \
        _Pragma("unroll") for (int j = 0; j < HH; j += 2) {                   \
            float s0 = bcastf(h2, j);                                         \
            float s1 = bcastf(h2, j + 1);                                     \
            q0 = fmaf(s0, whh2[j], q0);                                       \
            q1 = fmaf(s1, whh2[j + 1], q1);                                   \
        }                                                                     \
        acc2p = q0 + q1;                                                      \
    }

__global__ void __launch_bounds__(256, 1) rnn_fused(
    const float* __restrict__ x,     // [B,T,II]
    const float* __restrict__ Wih1,  // [H,II]
    const float* __restrict__ Whh1,  // [H,H]
    const float* __restrict__ bih1,
    const float* __restrict__ bhh1,
    const float* __restrict__ Wih2,  // [H,H]
    const float* __restrict__ Whh2,  // [H,H]
    const float* __restrict__ bih2,
    const float* __restrict__ bhh2,
    const float* __restrict__ Wfc1,  // [H,H]
    const float* __restrict__ bfc1,
    const float* __restrict__ Wfc2,  // [32,H]
    const float* __restrict__ bfc2,
    float* __restrict__ out)         // [B,32]
{
    const int wave = threadIdx.x >> 6;
    const int o = threadIdx.x & 63;             // lane == output component
    const int b = blockIdx.x * WPB + wave;      // batch element of this wave

    __shared__ __align__(16) float xs[WPB][2][CH * II];  // 4 x 2 x 8KB = 64KB

    // ---- weight rows into VGPRs (all indexing fully unrolled/constant) ----
    float wih1[II], whh1[HH], wih2[HH], whh2[HH];
    {
        const float4* p = (const float4*)(Wih1 + o * II);
#pragma unroll
        for (int k = 0; k < II / 4; ++k) {
            float4 v = p[k];
            wih1[4*k] = v.x; wih1[4*k+1] = v.y; wih1[4*k+2] = v.z; wih1[4*k+3] = v.w;
        }
    }
    {
        const float4* p = (const float4*)(Whh1 + o * HH);
#pragma unroll
        for (int k = 0; k < HH / 4; ++k) {
            float4 v = p[k];
            whh1[4*k] = v.x; whh1[4*k+1] = v.y; whh1[4*k+2] = v.z; whh1[4*k+3] = v.w;
        }
    }
    {
        const float4* p = (const float4*)(Wih2 + o * HH);
#pragma unroll
        for (int k = 0; k < HH / 4; ++k) {
            float4 v = p[k];
            wih2[4*k] = v.x; wih2[4*k+1] = v.y; wih2[4*k+2] = v.z; wih2[4*k+3] = v.w;
        }
    }
    {
        const float4* p = (const float4*)(Whh2 + o * HH);
#pragma unroll
        for (int k = 0; k < HH / 4; ++k) {
            float4 v = p[k];
            whh2[4*k] = v.x; whh2[4*k+1] = v.y; whh2[4*k+2] = v.z; whh2[4*k+3] = v.w;
        }
    }
    const float b1 = bih1[o] + bhh1[o];
    const float b2 = bih2[o] + bhh2[o];

    const float* xb = x + (size_t)b * TSTEPS * II;
    float* lds0 = &xs[wave][0][0];
    float* lds1 = &xs[wave][1][0];

    // prefetch chunk 0 and wait (per-wave vmcnt; waves are independent)
    stage8k(xb, lds0, o);
    asm volatile("s_waitcnt vmcnt(0)" ::: "memory");

    float h2 = 0.f;
    float acc1p = b1;  // carries b1 + Whh1 @ h1_{t-1}
    float acc2p = b2;  // carries b2 + Whh2 @ h2_{t-1}
    float4 xA[8], xB[8];

#pragma unroll 1
    for (int c = 0; c < NCH; ++c) {
        const float* cur = (c & 1) ? lds1 : lds0;
        float* nxt = (c & 1) ? lds0 : lds1;
        if (c + 1 < NCH) stage8k(xb + (c + 1) * CH * II, nxt, o);

        // software-pipelined x: A/B register rotation, prefetch distance 1
        LOADX(xA, cur);  // row 0 (latency exposed once per chunk only)
#pragma unroll 1
        for (int tt = 0; tt < CH - 2; tt += 2) {
            LOADX(xB, cur + (tt + 1) * II);
            STEP(xA);
            LOADX(xA, cur + (tt + 2) * II);
            STEP(xB);
        }
        // peeled chunk tail: rows CH-2, CH-1 (no prefetch past the buffer)
        LOADX(xB, cur + (CH - 1) * II);
        STEP(xA);
        STEP(xB);

        // staging for chunk c+1 must have landed before we read it
        asm volatile("s_waitcnt vmcnt(0)" ::: "memory");
    }

    // ---- FC head on final h2 (distributed: lane o holds h2[o]) ----
    float wf[HH];
    {
        const float4* p = (const float4*)(Wfc1 + o * HH);
#pragma unroll
        for (int k = 0; k < HH / 4; ++k) {
            float4 v = p[k];
            wf[4*k] = v.x; wf[4*k+1] = v.y; wf[4*k+2] = v.z; wf[4*k+3] = v.w;
        }
    }
    float z0 = bfc1[o], z1 = 0.f;
#pragma unroll
    for (int j = 0; j < HH; j += 2) {
        float s0 = bcastf(h2, j);
        float s1 = bcastf(h2, j + 1);
        z0 = fmaf(s0, wf[j],     z0);
        z1 = fmaf(s1, wf[j + 1], z1);
    }
    float z = fmaxf(z0 + z1, 0.f);

    const int oo = o & 31;  // lanes 32..63 duplicate rows 0..31 (not stored)
    {
        const float4* p = (const float4*)(Wfc2 + oo * HH);
#pragma unroll
        for (int k = 0; k < HH / 4; ++k) {
            float4 v = p[k];
            wf[4*k] = v.x; wf[4*k+1] = v.y; wf[4*k+2] = v.z; wf[4*k+3] = v.w;
        }
    }
    float y0 = bfc2[oo], y1 = 0.f;
#pragma unroll
    for (int j = 0; j < HH; j += 2) {
        float s0 = bcastf(z, j);
        float s1 = bcastf(z, j + 1);
        y0 = fmaf(s0, wf[j],     y0);
        y1 = fmaf(s1, wf[j + 1], y1);
    }
    if (o < 32) out[b * 32 + o] = y0 + y1;
}

extern "C" void kernel_launch(void* const* d_in, const int* in_sizes, int n_in,
                              void* d_out, int out_size, void* d_ws, size_t ws_size,
                              hipStream_t stream) {
    const float* x    = (const float*)d_in[0];
    const float* Wih1 = (const float*)d_in[1];
    const float* Whh1 = (const float*)d_in[2];
    const float* bih1 = (const float*)d_in[3];
    const float* bhh1 = (const float*)d_in[4];
    const float* Wih2 = (const float*)d_in[5];
    const float* Whh2 = (const float*)d_in[6];
    const float* bih2 = (const float*)d_in[7];
    const float* bhh2 = (const float*)d_in[8];
    const float* Wfc1 = (const float*)d_in[9];
    const float* bfc1 = (const float*)d_in[10];
    const float* Wfc2 = (const float*)d_in[11];
    const float* bfc2 = (const float*)d_in[12];
    float* out = (float*)d_out;

    hipLaunchKernelGGL(rnn_fused, dim3(BATCH / WPB), dim3(64 * WPB), 0, stream,
                       x, Wih1, Whh1, bih1, bhh1, Wih2, Whh2, bih2, bhh2,
                       Wfc1, bfc1, Wfc2, bfc2, out);
}